// Round 10
// baseline (5917.241 us; speedup 1.0000x reference)
//
#include <hip/hip_runtime.h>
#include <hip/hip_bf16.h>

typedef __attribute__((ext_vector_type(8))) short bf16x8;
typedef __attribute__((ext_vector_type(4))) float f32x4;

#define RING 4

__device__ __forceinline__ unsigned short f2bf(float f) {
  unsigned int u = __float_as_uint(f);
  unsigned int r = (u + 0x7FFFu + ((u >> 16) & 1u)) >> 16;
  return (unsigned short)r;
}

// --- coherence-point primitives (bypass L1/L2; round-4 proven protocol).
// Flag loads carry the waitcnt INSIDE the asm: the backend does not track
// asm vmem ops, so a bare load's result could be consumed before arrival.
__device__ __forceinline__ unsigned ldg_u32_coh_sync(const unsigned* p) {
  unsigned r;
  asm volatile("global_load_dword %0, %1, off sc0 sc1\n\t"
               "s_waitcnt vmcnt(0)"
               : "=v"(r) : "v"(p) : "memory");
  return r;
}
__device__ __forceinline__ bf16x8 ldg_b128_coh(const unsigned short* p) {
  bf16x8 r;
  asm volatile("global_load_dwordx4 %0, %1, off sc0 sc1" : "=v"(r) : "v"(p) : "memory");
  return r;
}
__device__ __forceinline__ f32x4 ldg_f4_coh(const float* p) {
  f32x4 r;
  asm volatile("global_load_dwordx4 %0, %1, off sc0 sc1" : "=v"(r) : "v"(p) : "memory");
  return r;
}
__device__ __forceinline__ void stg_f4_coh(float* p, f32x4 v) {
  asm volatile("global_store_dwordx4 %0, %1, off sc0 sc1" :: "v"(p), "v"(v) : "memory");
}
__device__ __forceinline__ void stg_b128_coh(unsigned short* p, bf16x8 v) {
  asm volatile("global_store_dwordx4 %0, %1, off sc0 sc1" :: "v"(p), "v"(v) : "memory");
}
__device__ __forceinline__ void stg_u32_coh(unsigned* p, unsigned v) {
  asm volatile("global_store_dword %0, %1, off sc0 sc1" :: "v"(p), "v"(v) : "memory");
}

// Producer/consumer persistent LSTM.
// 128 A-blocks: xpart[t] = x[t] @ Wx-slice  -> 4-deep LLC ring (off crit path)
// 128 B-blocks: gates = xpart[t] + h[t] @ Wh-slice + b -> h[t+1]
// Tile per block: 64 batch rows (rb half) x 16 j-cols (jb16). Weight slice
// (64 gate-cols x 1024 K, bf16 = 128 KB) staged once from raw f32 into LDS.
__global__ __launch_bounds__(512, 2) void lstm_persist(
    const float* __restrict__ x,
    const float* __restrict__ Wx,
    const float* __restrict__ Wh,
    const float* __restrict__ bias,
    unsigned short* __restrict__ h0,
    unsigned short* __restrict__ h1,
    float* __restrict__ out,
    unsigned* __restrict__ hflag,   // [128] B progress, uid = rb*64+jb16
    unsigned* __restrict__ aflag,   // [128] A progress
    float* __restrict__ xring)      // [128][RING][4096] f32 = 8 MB
{
  __shared__ unsigned short Wl[64][1032];   // 132,096 B
  __shared__ float gt[64][68];              // 17,408 B
  __shared__ unsigned short hst[64][16];    //  2,048 B

  const int tid  = threadIdx.x;
  const int bx   = blockIdx.x;
  const int xcd  = bx & 7;
  const int gidx = bx >> 3;
  const int role = gidx & 1;                  // 0 = A (x-side), 1 = B (h-side)
  const int uid  = (gidx >> 1) * 8 + xcd;     // 0..127, bijective per role
  const int rb   = uid >> 6;
  const int jb16 = uid & 63;
  const int row0 = rb * 64;

  // ---- one-time: stage weight slice from raw f32 global (no pack kernel)
  // Wl[c][k], c = jj*4 + g, j = jb16*16 + jj; src = W[(g*1024+k)*1024 + j]
  {
    const float* Wsrc = role ? Wh : Wx;
    for (int pass = 0; pass < 32; ++pass) {
      int gk = pass * 128 + (tid >> 2);        // 0..4095 = g*1024+k
      int jq = tid & 3;
      f32x4 v = *(const f32x4*)(Wsrc + (size_t)gk * 1024 + jb16 * 16 + jq * 4);
      int g = gk >> 10, k = gk & 1023;
      #pragma unroll
      for (int e = 0; e < 4; ++e)
        Wl[(jq * 4 + e) * 4 + g][k] = f2bf(v[e]);
    }
  }

  const int lane = tid & 63;
  const int w    = tid >> 6;
  const int wr   = w >> 1;       // 16-row tile 0..3
  const int wn   = w & 1;        // K parity
  const int a15  = lane & 15;
  const int hi   = lane >> 4;
  const int rowg = row0 + wr * 16 + a15;

  const int um0 = tid >> 4;      // 0..31 (elementwise rows um0, um0+32)
  const int um1 = um0 + 32;
  const int uj  = tid & 15;
  const int j0  = jb16 * 16 + uj;

  float* xr_base = xring + (size_t)uid * (RING * 4096);

  __syncthreads();

  if (role == 0) {
    // =================== A: x-projection producer ===================
    const float* xrow = x + (size_t)rowg * 512 * 1024;
    const unsigned* pflag = hflag + uid;   // partner B progress

    for (int t = 0; t < 512; ++t) {
      // ring throttle: writing slot t%4 overwrites xpart[t-4]; B consumed it
      // iff hflag >= t-3 (B finished step t-4 publishes t-3... publishes t-3? B finishing step s publishes s+1; need s = t-4 done -> hflag >= t-3).
      if (t > 3) {
        for (;;) {
          unsigned v = ldg_u32_coh_sync(pflag);
          if (v >= (unsigned)(t - 3)) break;
          __builtin_amdgcn_s_sleep(8);
        }
      }
      // x fragments f32 -> bf16 (normal cached loads, compiler-tracked)
      bf16x8 xreg[16];
      const float* xt = xrow + (size_t)t * 1024 + hi * 8;
      #pragma unroll
      for (int s = 0; s < 16; ++s) {
        const float* xp = xt + (2 * s + wn) * 32;
        f32x4 f0 = *(const f32x4*)xp;
        f32x4 f1 = *(const f32x4*)(xp + 4);
        union { bf16x8 v; unsigned short us[8]; } u;
        u.us[0] = f2bf(f0.x); u.us[1] = f2bf(f0.y);
        u.us[2] = f2bf(f0.z); u.us[3] = f2bf(f0.w);
        u.us[4] = f2bf(f1.x); u.us[5] = f2bf(f1.y);
        u.us[6] = f2bf(f1.z); u.us[7] = f2bf(f1.w);
        xreg[s] = u.v;
      }
      f32x4 acc[4] = {};
      #pragma unroll
      for (int s = 0; s < 16; ++s) {
        const int kk = (2 * s + wn) * 32 + hi * 8;
        #pragma unroll
        for (int n = 0; n < 4; ++n)
          acc[n] = __builtin_amdgcn_mfma_f32_16x16x32_bf16(
              xreg[s], *(const bf16x8*)&Wl[n * 16 + a15][kk], acc[n], 0, 0, 0);
      }
      // two-phase K-parity sum in LDS
      if (wn == 0) {
        #pragma unroll
        for (int n = 0; n < 4; ++n)
          #pragma unroll
          for (int r = 0; r < 4; ++r)
            gt[wr * 16 + hi * 4 + r][n * 16 + a15] = acc[n][r];
      }
      __syncthreads();
      if (wn == 1) {
        #pragma unroll
        for (int n = 0; n < 4; ++n)
          #pragma unroll
          for (int r = 0; r < 4; ++r)
            gt[wr * 16 + hi * 4 + r][n * 16 + a15] += acc[n][r];
      }
      __syncthreads();
      // publish 16 KB xpart tile, drain, barrier, flag (proven chain)
      float* xr = xr_base + (t & (RING - 1)) * 4096;
      stg_f4_coh(xr + um0 * 64 + uj * 4, *(const f32x4*)&gt[um0][uj * 4]);
      stg_f4_coh(xr + um1 * 64 + uj * 4, *(const f32x4*)&gt[um1][uj * 4]);
      asm volatile("s_waitcnt vmcnt(0)" ::: "memory");
      __syncthreads();
      if (tid == 0) stg_u32_coh(aflag + uid, (unsigned)(t + 1));
    }
  } else {
    // =================== B: recurrent consumer ===================
    const float bi = bias[j0], bf_ = bias[1024 + j0];
    const float bo = bias[2048 + j0], bu = bias[3072 + j0];
    float creg0 = 0.f, creg1 = 0.f;
    unsigned short* hb[2] = {h0, h1};
    const unsigned* myaf = aflag + uid;
    const unsigned* fp   = hflag + rb * 64 + lane;   // 64 same-rb flags

    for (int t = 0; t < 512; ++t) {
      const unsigned short* hc = hb[t & 1];
      unsigned short* hn = hb[(t + 1) & 1];

      // xpart[t] ready? (A runs ahead; usually instant)
      for (;;) {
        unsigned v = ldg_u32_coh_sync(myaf);
        if (v > (unsigned)t) break;
        __builtin_amdgcn_s_sleep(2);
      }
      const float* xr = xr_base + (t & (RING - 1)) * 4096;
      f32x4 xp0 = ldg_f4_coh(xr + um0 * 64 + uj * 4);
      f32x4 xp1 = ldg_f4_coh(xr + um1 * 64 + uj * 4);

      f32x4 acc[4] = {};
      if (t > 0) {
        // wait for all 64 same-rb B blocks to have published h[t]
        for (;;) {
          unsigned v = ldg_u32_coh_sync(fp);   // per-lane flag
          if (__all((int)(v >= (unsigned)t))) break;
          __builtin_amdgcn_s_sleep(1);
        }
        bf16x8 hreg[16];
        const unsigned short* hbase = hc + (size_t)rowg * 1024 + hi * 8;
        #pragma unroll
        for (int s = 0; s < 16; ++s)
          hreg[s] = ldg_b128_coh(hbase + (2 * s + wn) * 32);
        asm volatile("s_waitcnt vmcnt(0)" ::: "memory");
        __builtin_amdgcn_sched_barrier(0);
        #pragma unroll
        for (int s = 0; s < 16; ++s) {
          const int kk = (2 * s + wn) * 32 + hi * 8;
          #pragma unroll
          for (int n = 0; n < 4; ++n)
            acc[n] = __builtin_amdgcn_mfma_f32_16x16x32_bf16(
                hreg[s], *(const bf16x8*)&Wl[n * 16 + a15][kk], acc[n], 0, 0, 0);
        }
      }
      // two-phase K-parity sum (t=0: zeros)
      if (wn == 0) {
        #pragma unroll
        for (int n = 0; n < 4; ++n)
          #pragma unroll
          for (int r = 0; r < 4; ++r)
            gt[wr * 16 + hi * 4 + r][n * 16 + a15] = acc[n][r];
      }
      __syncthreads();
      if (wn == 1) {
        #pragma unroll
        for (int n = 0; n < 4; ++n)
          #pragma unroll
          for (int r = 0; r < 4; ++r)
            gt[wr * 16 + hi * 4 + r][n * 16 + a15] += acc[n][r];
      }
      __syncthreads();

      // drain xp loads (t=0 path has no other vmcnt before use)
      asm volatile("s_waitcnt vmcnt(0)" ::: "memory");
      __builtin_amdgcn_sched_barrier(0);

      // elementwise LSTM update (2 items per thread)
      f32x4 g0 = *(const f32x4*)&gt[um0][uj * 4];
      f32x4 g1 = *(const f32x4*)&gt[um1][uj * 4];
      float vi = g0.x + xp0.x + bi, vf = g0.y + xp0.y + bf_;
      float vo = g0.z + xp0.z + bo, vu = g0.w + xp0.w + bu;
      float iv = 1.f / (1.f + expf(-vi)), fv = 1.f / (1.f + expf(-vf));
      float ov = 1.f / (1.f + expf(-vo)), uv = tanhf(vu);
      creg0 = fv * creg0 + iv * uv;
      float hv0 = ov * tanhf(creg0);

      vi = g1.x + xp1.x + bi; vf = g1.y + xp1.y + bf_;
      vo = g1.z + xp1.z + bo; vu = g1.w + xp1.w + bu;
      iv = 1.f / (1.f + expf(-vi)); fv = 1.f / (1.f + expf(-vf));
      ov = 1.f / (1.f + expf(-vo)); uv = tanhf(vu);
      creg1 = fv * creg1 + iv * uv;
      float hv1 = ov * tanhf(creg1);

      if (t == 511) {
        out[(size_t)(row0 + um0) * 1024 + j0] = hv0;
        out[(size_t)(row0 + um1) * 1024 + j0] = hv1;
        break;
      }

      // stage h tile in LDS, then 128 x 16B vectorized coherent stores
      hst[um0][uj] = f2bf(hv0);
      hst[um1][uj] = f2bf(hv1);
      __syncthreads();
      if (tid < 128) {
        int row = tid >> 1, half = tid & 1;
        stg_b128_coh(hn + (size_t)(row0 + row) * 1024 + jb16 * 16 + half * 8,
                     *(const bf16x8*)&hst[row][half * 8]);
      }
      asm volatile("s_waitcnt vmcnt(0)" ::: "memory");   // drain h stores
      __syncthreads();                                   // all waves arrived
      if (tid == 0) stg_u32_coh(hflag + uid, (unsigned)(t + 1));
    }
  }
}

extern "C" void kernel_launch(void* const* d_in, const int* in_sizes, int n_in,
                              void* d_out, int out_size, void* d_ws, size_t ws_size,
                              hipStream_t stream) {
  const float* x    = (const float*)d_in[0];
  // d_in[1] = adjacency (unused)
  const float* Wx   = (const float*)d_in[2];
  const float* Wh   = (const float*)d_in[3];
  const float* bias = (const float*)d_in[4];
  float* out = (float*)d_out;

  // ws layout (bytes), total 8,921,088 — well under the proven-safe 17.3 MB:
  //   h0    @       0   262,144
  //   h1    @ 262,144   262,144
  //   hflag @ 524,288     4,096
  //   aflag @ 528,384     4,096
  //   xring @ 532,480 8,388,608  ([128][4][4096] f32)
  char* ws = (char*)d_ws;
  unsigned short* h0 = (unsigned short*)ws;
  unsigned short* h1 = (unsigned short*)(ws + 262144);
  unsigned* hflag = (unsigned*)(ws + 524288);
  unsigned* aflag = (unsigned*)(ws + 528384);
  float* xring = (float*)(ws + 532480);

  (void)hipMemsetAsync(h0, 0, 262144, stream);
  (void)hipMemsetAsync((void*)hflag, 0, 8192, stream);   // hflag + aflag

  (void)in_sizes; (void)n_in; (void)ws_size;
  lstm_persist<<<256, 512, 0, stream>>>(x, Wx, Wh, bias, h0, h1, out,
                                        hflag, aflag, xring);
}